// Round 1
// baseline (18473.459 us; speedup 1.0000x reference)
//
#include <hip/hip_runtime.h>
#include <math.h>

typedef unsigned short ushort_t;
typedef __attribute__((ext_vector_type(4))) float f32x4;
typedef __attribute__((ext_vector_type(8))) short s16x8;

// ---- workspace layout (bytes) ----
// xW   : [512][64][4096] bf16 (permuted gate cols, time-major)  268,435,456
// xb   : [64][512][1024] bf16                                    67,108,864
// wxp  : [4096][1024] bf16 (permuted rows, Wx part)               8,388,608
// whp  : [64][4][32][64][8] bf16 (per-block B-fragment order)     8,388,608
// bp   : [4096] f32 (permuted bias)                                  16,384
// hbuf : [2][64][1024] bf16                                         262,144
// cnt  : [4][512] int                                                 8,192
#define XW_OFF   0UL
#define XB_OFF   268435456UL
#define WXP_OFF  335544320UL
#define WHP_OFF  343932928UL
#define BP_OFF   352321536UL
#define HBUF_OFF 352337920UL
#define CNT_OFF  352600064UL

__device__ __forceinline__ ushort_t f2bf(float f) {
  unsigned u = __builtin_bit_cast(unsigned, f);
  unsigned r = u + 0x7FFFu + ((u >> 16) & 1u);
  return (ushort_t)(r >> 16);
}
__device__ __forceinline__ float bf2f(ushort_t h) {
  unsigned u = ((unsigned)h) << 16;
  return __builtin_bit_cast(float, u);
}
__device__ __forceinline__ float sigm(float x) { return 1.f / (1.f + __expf(-x)); }
__device__ __forceinline__ float tanh_f(float x) {
  float t = __expf(-2.f * fabsf(x));
  float r = (1.f - t) / (1.f + t);
  return x >= 0.f ? r : -r;
}
__device__ __forceinline__ void gload_lds16(const void* g, void* l) {
  __builtin_amdgcn_global_load_lds(
      (const __attribute__((address_space(1))) unsigned int*)g,
      (__attribute__((address_space(3))) unsigned int*)l, 16, 0, 0);
}

// ------------------- prep: x fp32 -> bf16 -------------------
__global__ __launch_bounds__(256) void convert_x(const float* __restrict__ x,
                                                 ushort_t* __restrict__ xb) {
  long gid = (long)blockIdx.x * 256 + threadIdx.x;   // 4,194,304 threads x 8 elems
  const float4* x4 = (const float4*)x;
  float4 f0 = x4[gid * 2];
  float4 f1 = x4[gid * 2 + 1];
  s16x8 o;
  o[0] = (short)f2bf(f0.x); o[1] = (short)f2bf(f0.y);
  o[2] = (short)f2bf(f0.z); o[3] = (short)f2bf(f0.w);
  o[4] = (short)f2bf(f1.x); o[5] = (short)f2bf(f1.y);
  o[6] = (short)f2bf(f1.z); o[7] = (short)f2bf(f1.w);
  ((s16x8*)xb)[gid] = o;
}

// ------------------- prep: pack W / bias, zero h & counters -------------------
// permutation: block kb owns h-cols [kb*16, kb*16+16); block-local col c in [0,64):
//   gate g = c&3, local col jj = c>>2, original W row G = g*1024 + kb*16 + jj
__global__ __launch_bounds__(256) void prep_pack(const float* __restrict__ W,
                                                 const float* __restrict__ bias,
                                                 ushort_t* __restrict__ wxp,
                                                 ushort_t* __restrict__ whp,
                                                 float* __restrict__ bp,
                                                 ushort_t* __restrict__ hbuf,
                                                 int* __restrict__ cnt) {
  long gid = (long)blockIdx.x * 256 + threadIdx.x;
  if (gid < 524288) {                    // whp fragments: [kb][w][kc][l][8]
    int l = gid & 63, kc = (int)((gid >> 6) & 31), w = (int)((gid >> 11) & 3);
    int kb = (int)(gid >> 13);
    int li = l & 15, quad = l >> 4;
    int colb = w * 16 + li;
    int G = (colb & 3) * 1024 + kb * 16 + (colb >> 2);
    int kk = kc * 32 + quad * 8;
    const float* src = W + (long)G * 2048 + 1024 + kk;
    ushort_t* dst = whp + gid * 8;
#pragma unroll
    for (int j = 0; j < 8; ++j) dst[j] = f2bf(src[j]);
  } else if (gid < 1048576) {            // wxp: [R][k8*8..]
    long id = gid - 524288;
    int k8 = (int)(id & 127);
    int R = (int)(id >> 7);
    int c = R & 63, kb = R >> 6;
    int G = (c & 3) * 1024 + kb * 16 + (c >> 2);
    const float* src = W + (long)G * 2048 + k8 * 8;
    ushort_t* dst = wxp + (long)R * 1024 + k8 * 8;
#pragma unroll
    for (int j = 0; j < 8; ++j) dst[j] = f2bf(src[j]);
  } else if (gid < 1048576 + 4096) {     // permuted bias
    int R = (int)(gid - 1048576);
    int c = R & 63, kb = R >> 6;
    int G = (c & 3) * 1024 + kb * 16 + (c >> 2);
    bp[R] = bias[G];
  } else if (gid < 1048576 + 4096 + 8192) {  // zero hbuf[0]
    long id = gid - 1048576 - 4096;
    s16x8 z = {0, 0, 0, 0, 0, 0, 0, 0};
    ((s16x8*)hbuf)[id] = z;
  } else if (gid < 1048576 + 4096 + 8192 + 2048) {  // zero counters
    cnt[gid - 1048576 - 4096 - 8192] = 0;
  }
}

// ------------------- phase 1: xW = x @ Wx^T + b  (bf16 MFMA, 128x128 tile) ----
__global__ __launch_bounds__(256) void lstm_phase1(const ushort_t* __restrict__ xb,
                                                   const ushort_t* __restrict__ wxp,
                                                   const float* __restrict__ bp,
                                                   ushort_t* __restrict__ xw) {
  __shared__ ushort_t As[16 * 512];  // 16KB: [c=mt*2+kcl][lane][8], fragment order
  __shared__ ushort_t Bs[16 * 512];
  int bid = blockIdx.x;
  int nt = bid & 31, mtb = bid >> 5;
  int n0 = nt * 128;
  int t0 = mtb * 2;
  int tid = threadIdx.x, w = tid >> 6, l = tid & 63;
  int quad = l >> 4, li = l & 15;
  int mh = w & 1, nh = w >> 1;
  f32x4 acc[4][4] = {};

  for (int k0 = 0; k0 < 1024; k0 += 64) {
    __syncthreads();
#pragma unroll
    for (int i = 0; i < 4; ++i) {
      int c = w * 4 + i;
      int mt = c >> 1, kcl = c & 1;
      int r = mt * 16 + li;
      int tt = t0 + (r >> 6), bb = r & 63;
      gload_lds16(xb + (long)(bb * 512 + tt) * 1024 + k0 + kcl * 32 + quad * 8,
                  &As[c * 512]);
      int rn = n0 + mt * 16 + li;
      gload_lds16(wxp + (long)rn * 1024 + k0 + kcl * 32 + quad * 8, &Bs[c * 512]);
    }
    __syncthreads();
#pragma unroll
    for (int kcl = 0; kcl < 2; ++kcl) {
      s16x8 av[4], bv[4];
#pragma unroll
      for (int i = 0; i < 4; ++i)
        av[i] = *(const s16x8*)&As[((mh * 4 + i) * 2 + kcl) * 512 + l * 8];
#pragma unroll
      for (int j = 0; j < 4; ++j)
        bv[j] = *(const s16x8*)&Bs[((nh * 4 + j) * 2 + kcl) * 512 + l * 8];
#pragma unroll
      for (int i = 0; i < 4; ++i)
#pragma unroll
        for (int j = 0; j < 4; ++j)
          acc[i][j] =
              __builtin_amdgcn_mfma_f32_16x16x32_bf16(av[i], bv[j], acc[i][j], 0, 0, 0);
    }
  }
  // epilogue: + bias, store bf16 to xw[t*64+b][R]
#pragma unroll
  for (int j = 0; j < 4; ++j) {
    float bj = bp[n0 + nh * 64 + j * 16 + li];
#pragma unroll
    for (int i = 0; i < 4; ++i) {
#pragma unroll
      for (int r = 0; r < 4; ++r) {
        int lr = mh * 64 + i * 16 + quad * 4 + r;
        long off = ((long)mtb * 128 + lr) * 4096 + (n0 + nh * 64 + j * 16 + li);
        xw[off] = f2bf(acc[i][j][r] + bj);
      }
    }
  }
}

// ------------------- phase 2: persistent recurrent scan -------------------
// 256 blocks: group gr = bid>>6 (16 batch rows), slice kb = bid&63 (16 h-cols).
// Wh slice held in 128 VGPRs/lane; h staged to LDS via global_load_lds;
// one device-scope sync per group per step.
__global__ __launch_bounds__(256) void lstm_phase2(const ushort_t* __restrict__ xw,
                                                   const ushort_t* __restrict__ whp,
                                                   ushort_t* __restrict__ hbuf,
                                                   float* __restrict__ out,
                                                   int* __restrict__ counters) {
  __shared__ ushort_t Aimg[32 * 512];  // 32KB h fragment image: [kc][lane][8]
  int bid = blockIdx.x;
  int gr = bid >> 6, kb = bid & 63;
  int tid = threadIdx.x, w = tid >> 6, l = tid & 63;
  int quad = l >> 4, li = l & 15;
  int colb = w * 16 + li;          // block-local gate col 0..63
  int gg = colb & 3;               // gate: 0=cand 1=f 2=u 3=o
  int jj = colb >> 2;              // local h col 0..15
  int colh = kb * 16 + jj;         // global h col

  // B fragments -> registers (stay live across all 512 steps)
  s16x8 bfr[32];
  const ushort_t* wp = whp + (long)(kb * 4 + w) * 32 * 512 + l * 8;
#pragma unroll
  for (int kc = 0; kc < 32; ++kc) bfr[kc] = *(const s16x8*)(wp + kc * 512);

  float cst[4] = {0.f, 0.f, 0.f, 0.f};
  // prefetch xw[t=0]
  ushort_t pf[4];
#pragma unroll
  for (int r = 0; r < 4; ++r)
    pf[r] = xw[(long)(gr * 16 + quad * 4 + r) * 4096 + kb * 64 + colb];

  int* cnt = counters + gr * 512;
  int base = l & ~3;

  for (int t = 0; t < 512; ++t) {
    int p = t & 1;
    const ushort_t* hsrc = hbuf + p * 65536 + gr * 16 * 1024;
#pragma unroll
    for (int ci = 0; ci < 8; ++ci) {
      int kc = w * 8 + ci;
      gload_lds16(hsrc + li * 1024 + kc * 32 + quad * 8, &Aimg[kc * 512]);
    }
    f32x4 a0, a1, a2, a3;
#pragma unroll
    for (int r = 0; r < 4; ++r) a0[r] = bf2f(pf[r]);
    a1 = (f32x4)0.f; a2 = (f32x4)0.f; a3 = (f32x4)0.f;
    if (t < 511) {
#pragma unroll
      for (int r = 0; r < 4; ++r)
        pf[r] = xw[(long)((t + 1) * 64 + gr * 16 + quad * 4 + r) * 4096 + kb * 64 + colb];
    }
    __syncthreads();  // drains global_load_lds (vmcnt) + prior barrier semantics
#pragma unroll
    for (int kc = 0; kc < 32; ++kc) {
      s16x8 a = *(const s16x8*)&Aimg[kc * 512 + l * 8];
      switch (kc & 3) {
        case 0: a0 = __builtin_amdgcn_mfma_f32_16x16x32_bf16(a, bfr[kc], a0, 0, 0, 0); break;
        case 1: a1 = __builtin_amdgcn_mfma_f32_16x16x32_bf16(a, bfr[kc], a1, 0, 0, 0); break;
        case 2: a2 = __builtin_amdgcn_mfma_f32_16x16x32_bf16(a, bfr[kc], a2, 0, 0, 0); break;
        default: a3 = __builtin_amdgcn_mfma_f32_16x16x32_bf16(a, bfr[kc], a3, 0, 0, 0); break;
      }
    }
    f32x4 pre4 = (a0 + a1) + (a2 + a3);

    float hn[4], cn[4];
#pragma unroll
    for (int r = 0; r < 4; ++r) {
      float pre = pre4[r];
      float candp = __shfl(pre, base + 0, 64);
      float fp_ = __shfl(pre, base + 1, 64);
      float up = __shfl(pre, base + 2, 64);
      float op = __shfl(pre, base + 3, 64);
      float c_ = sigm(up) * tanh_f(candp) + sigm(fp_) * cst[r];
      cst[r] = c_;
      cn[r] = c_;
      hn[r] = sigm(op) * tanh_f(c_);
    }
    ushort_t* hdst = hbuf + (p ^ 1) * 65536;
    if (gg == 0) {
#pragma unroll
      for (int r = 0; r < 4; ++r) {
        int b = gr * 16 + quad * 4 + r;
        hdst[b * 1024 + colh] = f2bf(hn[r]);
        out[((long)b * 512 + t) * 1024 + colh] = hn[r];
        if (t == 511) {
          out[33554432 + b * 1024 + colh] = hn[r];
          out[33619968 + b * 1024 + colh] = cn[r];
        }
      }
    }
    __threadfence();
    __syncthreads();
    if (tid == 0) {
      __hip_atomic_fetch_add(cnt + t, 1, __ATOMIC_RELEASE, __HIP_MEMORY_SCOPE_AGENT);
      while (__hip_atomic_load(cnt + t, __ATOMIC_ACQUIRE, __HIP_MEMORY_SCOPE_AGENT) < 64)
        __builtin_amdgcn_s_sleep(2);
    }
    __syncthreads();
  }
}

extern "C" void kernel_launch(void* const* d_in, const int* in_sizes, int n_in,
                              void* d_out, int out_size, void* d_ws, size_t ws_size,
                              hipStream_t stream) {
  const float* x = (const float*)d_in[0];
  const float* W = (const float*)d_in[1];
  const float* b = (const float*)d_in[2];
  float* out = (float*)d_out;
  char* ws = (char*)d_ws;
  ushort_t* xw = (ushort_t*)(ws + XW_OFF);
  ushort_t* xb = (ushort_t*)(ws + XB_OFF);
  ushort_t* wxp = (ushort_t*)(ws + WXP_OFF);
  ushort_t* whp = (ushort_t*)(ws + WHP_OFF);
  float* bp = (float*)(ws + BP_OFF);
  ushort_t* hbuf = (ushort_t*)(ws + HBUF_OFF);
  int* cnt = (int*)(ws + CNT_OFF);

  convert_x<<<16384, 256, 0, stream>>>(x, xb);
  prep_pack<<<4152, 256, 0, stream>>>(W, b, wxp, whp, bp, hbuf, cnt);
  lstm_phase1<<<8192, 256, 0, stream>>>(xb, wxp, bp, xw);
  lstm_phase2<<<256, 256, 0, stream>>>(xw, whp, hbuf, out, cnt);
}

// Round 2
// 6539.957 us; speedup vs baseline: 2.8247x; 2.8247x over previous
//
#include <hip/hip_runtime.h>
#include <math.h>

typedef unsigned short ushort_t;
typedef __attribute__((ext_vector_type(4))) float f32x4;
typedef __attribute__((ext_vector_type(8))) short s16x8;

// ---- workspace layout (bytes) ----
// xW   : [512][64][4096] bf16 (permuted gate cols, time-major)  268,435,456
// xb   : [64][512][1024] bf16                                    67,108,864
// wxp  : [4096][1024] bf16 (permuted rows, Wx part)               8,388,608
// whp  : [64][4][32][64][8] bf16 (per-block B-fragment order)     8,388,608
// bp   : [4096] f32 (permuted bias)                                  16,384
// hbuf : [2][64][1024] bf16                                         262,144
// cnt  : [4][512] int                                                 8,192
#define XW_OFF   0UL
#define XB_OFF   268435456UL
#define WXP_OFF  335544320UL
#define WHP_OFF  343932928UL
#define BP_OFF   352321536UL
#define HBUF_OFF 352337920UL
#define CNT_OFF  352600064UL

__device__ __forceinline__ ushort_t f2bf(float f) {
  unsigned u = __builtin_bit_cast(unsigned, f);
  unsigned r = u + 0x7FFFu + ((u >> 16) & 1u);
  return (ushort_t)(r >> 16);
}
__device__ __forceinline__ float bf2f(ushort_t h) {
  unsigned u = ((unsigned)h) << 16;
  return __builtin_bit_cast(float, u);
}
__device__ __forceinline__ float sigm(float x) { return 1.f / (1.f + __expf(-x)); }
__device__ __forceinline__ float tanh_f(float x) {
  float t = __expf(-2.f * fabsf(x));
  float r = (1.f - t) / (1.f + t);
  return x >= 0.f ? r : -r;
}
__device__ __forceinline__ void gload_lds16(const void* g, void* l) {
  __builtin_amdgcn_global_load_lds(
      (const __attribute__((address_space(1))) unsigned int*)g,
      (__attribute__((address_space(3))) unsigned int*)l, 16, 0, 0);
}

// ------------------- prep: x fp32 -> bf16 -------------------
__global__ __launch_bounds__(256) void convert_x(const float* __restrict__ x,
                                                 ushort_t* __restrict__ xb) {
  long gid = (long)blockIdx.x * 256 + threadIdx.x;   // 4,194,304 threads x 8 elems
  const float4* x4 = (const float4*)x;
  float4 f0 = x4[gid * 2];
  float4 f1 = x4[gid * 2 + 1];
  s16x8 o;
  o[0] = (short)f2bf(f0.x); o[1] = (short)f2bf(f0.y);
  o[2] = (short)f2bf(f0.z); o[3] = (short)f2bf(f0.w);
  o[4] = (short)f2bf(f1.x); o[5] = (short)f2bf(f1.y);
  o[6] = (short)f2bf(f1.z); o[7] = (short)f2bf(f1.w);
  ((s16x8*)xb)[gid] = o;
}

// ------------------- prep: pack W / bias, zero h & counters -------------------
// permutation: block kb owns h-cols [kb*16, kb*16+16); block-local col c in [0,64):
//   gate g = c&3, local col jj = c>>2, original W row G = g*1024 + kb*16 + jj
__global__ __launch_bounds__(256) void prep_pack(const float* __restrict__ W,
                                                 const float* __restrict__ bias,
                                                 ushort_t* __restrict__ wxp,
                                                 ushort_t* __restrict__ whp,
                                                 float* __restrict__ bp,
                                                 ushort_t* __restrict__ hbuf,
                                                 int* __restrict__ cnt) {
  long gid = (long)blockIdx.x * 256 + threadIdx.x;
  if (gid < 524288) {                    // whp fragments: [kb][w][kc][l][8]
    int l = gid & 63, kc = (int)((gid >> 6) & 31), w = (int)((gid >> 11) & 3);
    int kb = (int)(gid >> 13);
    int li = l & 15, quad = l >> 4;
    int colb = w * 16 + li;
    int G = (colb & 3) * 1024 + kb * 16 + (colb >> 2);
    int kk = kc * 32 + quad * 8;
    const float* src = W + (long)G * 2048 + 1024 + kk;
    ushort_t* dst = whp + gid * 8;
#pragma unroll
    for (int j = 0; j < 8; ++j) dst[j] = f2bf(src[j]);
  } else if (gid < 1048576) {            // wxp: [R][k8*8..]
    long id = gid - 524288;
    int k8 = (int)(id & 127);
    int R = (int)(id >> 7);
    int c = R & 63, kb = R >> 6;
    int G = (c & 3) * 1024 + kb * 16 + (c >> 2);
    const float* src = W + (long)G * 2048 + k8 * 8;
    ushort_t* dst = wxp + (long)R * 1024 + k8 * 8;
#pragma unroll
    for (int j = 0; j < 8; ++j) dst[j] = f2bf(src[j]);
  } else if (gid < 1048576 + 4096) {     // permuted bias
    int R = (int)(gid - 1048576);
    int c = R & 63, kb = R >> 6;
    int G = (c & 3) * 1024 + kb * 16 + (c >> 2);
    bp[R] = bias[G];
  } else if (gid < 1048576 + 4096 + 8192) {  // zero hbuf[0]
    long id = gid - 1048576 - 4096;
    s16x8 z = {0, 0, 0, 0, 0, 0, 0, 0};
    ((s16x8*)hbuf)[id] = z;
  } else if (gid < 1048576 + 4096 + 8192 + 2048) {  // zero counters
    cnt[gid - 1048576 - 4096 - 8192] = 0;
  }
}

// ------------------- phase 1: xW = x @ Wx^T + b  (bf16 MFMA, 128x128 tile) ----
__global__ __launch_bounds__(256) void lstm_phase1(const ushort_t* __restrict__ xb,
                                                   const ushort_t* __restrict__ wxp,
                                                   const float* __restrict__ bp,
                                                   ushort_t* __restrict__ xw) {
  __shared__ ushort_t As[16 * 512];  // 16KB: [c=mt*2+kcl][lane][8], fragment order
  __shared__ ushort_t Bs[16 * 512];
  int bid = blockIdx.x;
  int nt = bid & 31, mtb = bid >> 5;
  int n0 = nt * 128;
  int t0 = mtb * 2;
  int tid = threadIdx.x, w = tid >> 6, l = tid & 63;
  int quad = l >> 4, li = l & 15;
  int mh = w & 1, nh = w >> 1;
  f32x4 acc[4][4] = {};

  for (int k0 = 0; k0 < 1024; k0 += 64) {
    __syncthreads();
#pragma unroll
    for (int i = 0; i < 4; ++i) {
      int c = w * 4 + i;
      int mt = c >> 1, kcl = c & 1;
      int r = mt * 16 + li;
      int tt = t0 + (r >> 6), bb = r & 63;
      gload_lds16(xb + (long)(bb * 512 + tt) * 1024 + k0 + kcl * 32 + quad * 8,
                  &As[c * 512]);
      int rn = n0 + mt * 16 + li;
      gload_lds16(wxp + (long)rn * 1024 + k0 + kcl * 32 + quad * 8, &Bs[c * 512]);
    }
    __syncthreads();
#pragma unroll
    for (int kcl = 0; kcl < 2; ++kcl) {
      s16x8 av[4], bv[4];
#pragma unroll
      for (int i = 0; i < 4; ++i)
        av[i] = *(const s16x8*)&As[((mh * 4 + i) * 2 + kcl) * 512 + l * 8];
#pragma unroll
      for (int j = 0; j < 4; ++j)
        bv[j] = *(const s16x8*)&Bs[((nh * 4 + j) * 2 + kcl) * 512 + l * 8];
#pragma unroll
      for (int i = 0; i < 4; ++i)
#pragma unroll
        for (int j = 0; j < 4; ++j)
          acc[i][j] =
              __builtin_amdgcn_mfma_f32_16x16x32_bf16(av[i], bv[j], acc[i][j], 0, 0, 0);
    }
  }
  // epilogue: + bias, store bf16 to xw[t*64+b][R]
#pragma unroll
  for (int j = 0; j < 4; ++j) {
    float bj = bp[n0 + nh * 64 + j * 16 + li];
#pragma unroll
    for (int i = 0; i < 4; ++i) {
#pragma unroll
      for (int r = 0; r < 4; ++r) {
        int lr = mh * 64 + i * 16 + quad * 4 + r;
        long off = ((long)mtb * 128 + lr) * 4096 + (n0 + nh * 64 + j * 16 + li);
        xw[off] = f2bf(acc[i][j][r] + bj);
      }
    }
  }
}

// ------------------- phase 2: persistent recurrent scan -------------------
// 256 blocks: group gr = bid>>6 (16 batch rows), slice kb = bid&63 (16 h-cols).
// Wh slice held in VGPRs; h staged to LDS via global_load_lds.
// Sync protocol (ONE wbl2 + ONE inv per block per step):
//   plain h stores -> per-wave vmcnt(0) -> barrier -> wave0: RELEASE fetch_add
//   (waitcnt + buffer_wbl2 + RMW) -> RELAXED spin (no cache maintenance) ->
//   one ACQUIRE load (buffer_inv) -> barrier -> next step's plain loads see
//   fresh h. Round 1 spent ~35us/step because the ACQUIRE spin emitted
//   buffer_inv EVERY poll, thrashing L2 device-wide.
__global__ __launch_bounds__(256) void lstm_phase2(const ushort_t* __restrict__ xw,
                                                   const ushort_t* __restrict__ whp,
                                                   ushort_t* __restrict__ hbuf,
                                                   float* __restrict__ out,
                                                   int* __restrict__ counters) {
  __shared__ ushort_t Aimg[32 * 512];  // 32KB h fragment image: [kc][lane][8]
  int bid = blockIdx.x;
  int gr = bid >> 6, kb = bid & 63;
  int tid = threadIdx.x, w = tid >> 6, l = tid & 63;
  int quad = l >> 4, li = l & 15;
  int colb = w * 16 + li;          // block-local gate col 0..63
  int gg = colb & 3;               // gate: 0=cand 1=f 2=u 3=o
  int jj = colb >> 2;              // local h col 0..15
  int colh = kb * 16 + jj;         // global h col

  // B fragments -> registers (stay live across all 512 steps)
  s16x8 bfr[32];
  const ushort_t* wp = whp + (long)(kb * 4 + w) * 32 * 512 + l * 8;
#pragma unroll
  for (int kc = 0; kc < 32; ++kc) bfr[kc] = *(const s16x8*)(wp + kc * 512);

  float cst[4] = {0.f, 0.f, 0.f, 0.f};
  // prefetch xw[t=0]
  ushort_t pf[4];
#pragma unroll
  for (int r = 0; r < 4; ++r)
    pf[r] = xw[(long)(gr * 16 + quad * 4 + r) * 4096 + kb * 64 + colb];

  int* cnt = counters + gr * 512;
  int base = l & ~3;

  for (int t = 0; t < 512; ++t) {
    int p = t & 1;
    const ushort_t* hsrc = hbuf + p * 65536 + gr * 16 * 1024;
#pragma unroll
    for (int ci = 0; ci < 8; ++ci) {
      int kc = w * 8 + ci;
      gload_lds16(hsrc + li * 1024 + kc * 32 + quad * 8, &Aimg[kc * 512]);
    }
    f32x4 a0, a1, a2, a3;
#pragma unroll
    for (int r = 0; r < 4; ++r) a0[r] = bf2f(pf[r]);
    a1 = (f32x4)0.f; a2 = (f32x4)0.f; a3 = (f32x4)0.f;
    if (t < 511) {
#pragma unroll
      for (int r = 0; r < 4; ++r)
        pf[r] = xw[(long)((t + 1) * 64 + gr * 16 + quad * 4 + r) * 4096 + kb * 64 + colb];
    }
    __syncthreads();  // drains global_load_lds (vmcnt) + prior barrier semantics
#pragma unroll
    for (int kc = 0; kc < 32; ++kc) {
      s16x8 a = *(const s16x8*)&Aimg[kc * 512 + l * 8];
      switch (kc & 3) {
        case 0: a0 = __builtin_amdgcn_mfma_f32_16x16x32_bf16(a, bfr[kc], a0, 0, 0, 0); break;
        case 1: a1 = __builtin_amdgcn_mfma_f32_16x16x32_bf16(a, bfr[kc], a1, 0, 0, 0); break;
        case 2: a2 = __builtin_amdgcn_mfma_f32_16x16x32_bf16(a, bfr[kc], a2, 0, 0, 0); break;
        default: a3 = __builtin_amdgcn_mfma_f32_16x16x32_bf16(a, bfr[kc], a3, 0, 0, 0); break;
      }
    }
    f32x4 pre4 = (a0 + a1) + (a2 + a3);

    float hn[4], cn[4];
#pragma unroll
    for (int r = 0; r < 4; ++r) {
      float pre = pre4[r];
      float candp = __shfl(pre, base + 0, 64);
      float fp_ = __shfl(pre, base + 1, 64);
      float up = __shfl(pre, base + 2, 64);
      float op = __shfl(pre, base + 3, 64);
      float c_ = sigm(up) * tanh_f(candp) + sigm(fp_) * cst[r];
      cst[r] = c_;
      cn[r] = c_;
      hn[r] = sigm(op) * tanh_f(c_);
    }
    ushort_t* hdst = hbuf + (p ^ 1) * 65536;
    if (gg == 0) {
#pragma unroll
      for (int r = 0; r < 4; ++r) {
        int b = gr * 16 + quad * 4 + r;
        hdst[b * 1024 + colh] = f2bf(hn[r]);
        out[((long)b * 512 + t) * 1024 + colh] = hn[r];
        if (t == 511) {
          out[33554432 + b * 1024 + colh] = hn[r];
          out[33619968 + b * 1024 + colh] = cn[r];
        }
      }
    }
    // per-wave: make sure this wave's h stores have reached L2 before barrier
    asm volatile("s_waitcnt vmcnt(0)" ::: "memory");
    __syncthreads();
    if (tid == 0) {
      // RELEASE RMW: waitcnt + buffer_wbl2 (flush L2 once) + atomic add
      __hip_atomic_fetch_add(cnt + t, 1, __ATOMIC_RELEASE, __HIP_MEMORY_SCOPE_AGENT);
      // RELAXED spin: plain coherent polls, NO buffer_inv per iteration
      while (__hip_atomic_load(cnt + t, __ATOMIC_RELAXED, __HIP_MEMORY_SCOPE_AGENT) < 64)
        __builtin_amdgcn_s_sleep(1);
      // ONE acquire (buffer_inv) so next step's plain loads see fresh h
      (void)__hip_atomic_load(cnt + t, __ATOMIC_ACQUIRE, __HIP_MEMORY_SCOPE_AGENT);
    }
    __syncthreads();
  }
}

extern "C" void kernel_launch(void* const* d_in, const int* in_sizes, int n_in,
                              void* d_out, int out_size, void* d_ws, size_t ws_size,
                              hipStream_t stream) {
  const float* x = (const float*)d_in[0];
  const float* W = (const float*)d_in[1];
  const float* b = (const float*)d_in[2];
  float* out = (float*)d_out;
  char* ws = (char*)d_ws;
  ushort_t* xw = (ushort_t*)(ws + XW_OFF);
  ushort_t* xb = (ushort_t*)(ws + XB_OFF);
  ushort_t* wxp = (ushort_t*)(ws + WXP_OFF);
  ushort_t* whp = (ushort_t*)(ws + WHP_OFF);
  float* bp = (float*)(ws + BP_OFF);
  ushort_t* hbuf = (ushort_t*)(ws + HBUF_OFF);
  int* cnt = (int*)(ws + CNT_OFF);

  convert_x<<<16384, 256, 0, stream>>>(x, xb);
  prep_pack<<<4152, 256, 0, stream>>>(W, b, wxp, whp, bp, hbuf, cnt);
  lstm_phase1<<<8192, 256, 0, stream>>>(xb, wxp, bp, xw);
  lstm_phase2<<<256, 256, 0, stream>>>(xw, whp, hbuf, out, cnt);
}